// Round 2
// baseline (9075.164 us; speedup 1.0000x reference)
//
#include <hip/hip_runtime.h>
#include <math.h>

// DigitCaps dynamic routing, fused (u_hat never materialized — not even in
// registers). B=512, I=1152, K=8, C=10, D=16, 3 routing iters.
//
// R1 lesson: uh[160] per thread spilled to scratch (23 GB WRITE/pass, VALUBusy
// 3.7%). R2: recompute h = <W_row, u> in both the logit phase and the
// s-accumulation phase; only coef[10]/logit[10] live in registers.
//
// Mapping: block=256; bl = t&31 picks b within a 32-b tile, stripe = t>>5
// picks i; each thread handles i0 = ibase+stripe and i1 = i0+8 jointly
// (shares the v-read and the ds_add between them). Grid (72, 16).
// s accumulated in LDS [cd][bl] pitch 33 (conflict-free), flushed as
// per-block partials, reduced+squashed in a second kernel.

#define CD 160
#define LDS_PITCH 33
#define NB_B 32
#define ICHUNK 16
#define NCH (1152 / ICHUNK)   // 72

__device__ __forceinline__ float dot8(const float* __restrict__ w,
                                      const float4 ua, const float4 ub) {
    const float4* wp = (const float4*)w;
    const float4 w0 = wp[0];
    const float4 w1 = wp[1];
    return w0.x * ua.x + w0.y * ua.y + w0.z * ua.z + w0.w * ua.w
         + w1.x * ub.x + w1.y * ub.y + w1.z * ub.z + w1.w * ub.w;
}

__device__ __forceinline__ void softmax10(const float* __restrict__ l,
                                          float* __restrict__ coef) {
    float m = l[0];
    #pragma unroll
    for (int c = 1; c < 10; ++c) m = fmaxf(m, l[c]);
    float ssum = 0.0f;
    #pragma unroll
    for (int c = 0; c < 10; ++c) {
        float e = __expf(l[c] - m);
        coef[c] = e;
        ssum += e;
    }
    float r = 1.0f / ssum;
    #pragma unroll
    for (int c = 0; c < 10; ++c) coef[c] *= r;
}

template <int PASS>
__global__ __launch_bounds__(256, 3)
void pass_kernel(const float* __restrict__ u, const float* __restrict__ W,
                 const float* __restrict__ v0g, const float* __restrict__ v1g,
                 float* __restrict__ part, float* __restrict__ s_atomic)
{
    __shared__ float s_tile[CD * LDS_PITCH];
    __shared__ float v_t[CD * LDS_PITCH];   // v0 (pass1) or v0+v1 (pass2)

    const int t      = threadIdx.x;
    const int bl     = t & 31;
    const int stripe = t >> 5;
    const int b0     = blockIdx.y * NB_B;
    const int b      = b0 + bl;
    const int ibase  = blockIdx.x * ICHUNK;

    for (int idx = t; idx < CD * LDS_PITCH; idx += 256) s_tile[idx] = 0.0f;
    if (PASS >= 1) {
        for (int idx = t; idx < NB_B * CD; idx += 256) {
            int b_l = idx / CD, cd = idx - b_l * CD;
            float v = v0g[(size_t)(b0 + b_l) * CD + cd];
            if (PASS >= 2) v += v1g[(size_t)(b0 + b_l) * CD + cd];
            v_t[cd * LDS_PITCH + b_l] = v;
        }
    }
    __syncthreads();

    const int i0 = ibase + stripe;
    const int i1 = i0 + 8;

    const float4* up0 = (const float4*)(u + ((size_t)b * 1152 + i0) * 8);
    const float4* up1 = (const float4*)(u + ((size_t)b * 1152 + i1) * 8);
    const float4 u0a = up0[0], u0b = up0[1];
    const float4 u1a = up1[0], u1b = up1[1];

    const float* W0 = W + (size_t)i0 * (10 * 16 * 8);
    const float* W1 = W + (size_t)i1 * (10 * 16 * 8);

    float coef0[10], coef1[10];

    if (PASS == 0) {
        #pragma unroll
        for (int c = 0; c < 10; ++c) { coef0[c] = 0.1f; coef1[c] = 0.1f; }
    } else {
        float l0[10], l1[10];
        #pragma unroll
        for (int c = 0; c < 10; ++c) {
            float a0 = 0.0f, a1 = 0.0f;
            #pragma unroll
            for (int d = 0; d < 16; ++d) {
                const int row = c * 16 + d;
                const float vv = v_t[row * LDS_PITCH + bl];
                const float h0 = dot8(W0 + row * 8, u0a, u0b);
                const float h1 = dot8(W1 + row * 8, u1a, u1b);
                a0 += h0 * vv;
                a1 += h1 * vv;
            }
            l0[c] = a0;
            l1[c] = a1;
        }
        softmax10(l0, coef0);
        softmax10(l1, coef1);
    }

    #pragma unroll
    for (int c = 0; c < 10; ++c) {
        #pragma unroll
        for (int d = 0; d < 16; ++d) {
            const int row = c * 16 + d;
            const float h0 = dot8(W0 + row * 8, u0a, u0b);
            const float h1 = dot8(W1 + row * 8, u1a, u1b);
#if defined(__HIP_DEVICE_COMPILE__)
            unsafeAtomicAdd(&s_tile[row * LDS_PITCH + bl],
                            coef0[c] * h0 + coef1[c] * h1);
#endif
        }
    }
    __syncthreads();

    if (part) {
        // Non-atomic per-block partial: part[(chunk*512 + b)*160 + cd]
        float* pout = part + ((size_t)blockIdx.x * 512 + b0) * CD;
        for (int idx = t; idx < NB_B * CD; idx += 256) {
            int b_l = idx / CD, cd = idx - b_l * CD;
            pout[idx] = s_tile[cd * LDS_PITCH + b_l];
        }
    } else {
        for (int idx = t; idx < NB_B * CD; idx += 256) {
            int b_l = idx / CD, cd = idx - b_l * CD;
#if defined(__HIP_DEVICE_COMPILE__)
            unsafeAtomicAdd(&s_atomic[(size_t)(b0 + b_l) * CD + cd],
                            s_tile[cd * LDS_PITCH + b_l]);
#endif
        }
    }
}

// Reduce 72 partials and apply squash. 8 b-rows per block, grid 64.
__global__ void reduce_squash(const float* __restrict__ part, float* __restrict__ vout)
{
    __shared__ float acc_s[8 * CD];
    const int t  = threadIdx.x;
    const int b0 = blockIdx.x * 8;

    float acc[5] = {0.f, 0.f, 0.f, 0.f, 0.f};
    for (int ch = 0; ch < NCH; ++ch) {
        const float* p = part + ((size_t)ch * 512 + b0) * CD;
        #pragma unroll
        for (int j = 0; j < 5; ++j) acc[j] += p[t + 256 * j];
    }
    #pragma unroll
    for (int j = 0; j < 5; ++j) acc_s[t + 256 * j] = acc[j];
    __syncthreads();

    if (t < 80) {   // 8 b x 10 c rows
        float sv[16];
        float ns = 0.0f;
        #pragma unroll
        for (int d = 0; d < 16; ++d) {
            float x = acc_s[t * 16 + d];
            sv[d] = x;
            ns += x * x;
        }
        float scale = ns / ((1.0f + ns) * (sqrtf(ns) + 1e-8f));
        float* o = vout + ((size_t)b0 * 10 + t) * 16;
        #pragma unroll
        for (int d = 0; d < 16; ++d) o[d] = sv[d] * scale;
    }
}

// Fallback squash (atomic path): one thread per (b,c) row.
__global__ void squash_only(const float* __restrict__ s, float* __restrict__ vout)
{
    int r = blockIdx.x * 256 + threadIdx.x;
    if (r >= 512 * 10) return;
    const float* sp = s + (size_t)r * 16;
    float sv[16];
    float ns = 0.0f;
    #pragma unroll
    for (int d = 0; d < 16; ++d) {
        float x = sp[d];
        sv[d] = x;
        ns += x * x;
    }
    float scale = ns / ((1.0f + ns) * (sqrtf(ns) + 1e-8f));
    float* o = vout + (size_t)r * 16;
    #pragma unroll
    for (int d = 0; d < 16; ++d) o[d] = sv[d] * scale;
}

extern "C" void kernel_launch(void* const* d_in, const int* in_sizes, int n_in,
                              void* d_out, int out_size, void* d_ws, size_t ws_size,
                              hipStream_t stream)
{
    const float* u = (const float*)d_in[0];   // [512,1152,8]
    const float* W = (const float*)d_in[1];   // [1152,10,16,8]
    float* out = (float*)d_out;               // [512,10,16]

    float* v0 = (float*)d_ws;                 // 81920 f32
    float* v1 = v0 + 81920;                   // 81920 f32

    const size_t needA = ((size_t)2 * 81920 + (size_t)NCH * 512 * CD) * sizeof(float); // ~24.3 MB

    dim3 grid(NCH, 16);
    dim3 blk(256);

    if (ws_size >= needA) {
        float* part = v1 + 81920;             // [72][512][160] f32
        pass_kernel<0><<<grid, blk, 0, stream>>>(u, W, nullptr, nullptr, part, nullptr);
        reduce_squash<<<64, 256, 0, stream>>>(part, v0);
        pass_kernel<1><<<grid, blk, 0, stream>>>(u, W, v0, nullptr, part, nullptr);
        reduce_squash<<<64, 256, 0, stream>>>(part, v1);
        pass_kernel<2><<<grid, blk, 0, stream>>>(u, W, v0, v1, part, nullptr);
        reduce_squash<<<64, 256, 0, stream>>>(part, out);
    } else {
        // Low-workspace fallback: single s buffer + global fp32 atomics.
        float* s = v1 + 81920;                // 81920 f32
        hipMemsetAsync(s, 0, 81920 * sizeof(float), stream);
        pass_kernel<0><<<grid, blk, 0, stream>>>(u, W, nullptr, nullptr, nullptr, s);
        squash_only<<<20, 256, 0, stream>>>(s, v0);
        hipMemsetAsync(s, 0, 81920 * sizeof(float), stream);
        pass_kernel<1><<<grid, blk, 0, stream>>>(u, W, v0, nullptr, nullptr, s);
        squash_only<<<20, 256, 0, stream>>>(s, v1);
        hipMemsetAsync(s, 0, 81920 * sizeof(float), stream);
        pass_kernel<2><<<grid, blk, 0, stream>>>(u, W, v0, v1, nullptr, s);
        squash_only<<<20, 256, 0, stream>>>(s, out);
    }
}

// Round 3
// 1378.254 us; speedup vs baseline: 6.5845x; 6.5845x over previous
//
#include <hip/hip_runtime.h>
#include <math.h>

// DigitCaps dynamic routing. B=512, I=1152, K=8, C=10, D=16, 3 iters.
//
// R1: uh[160]/thread -> scratch spill. R2: dot8 recompute CSE'd across the
// softmax -> 320 live floats -> 5.87 GB/pass scratch writes, VALUBusy 1%.
// R3: thread owns (b, c) — only a 16-wide cd slice. Registers: h[16] (this
// (b,i,c) row), v[16] (i-invariant, loaded once), s_acc[16] (accumulated
// over the whole i-chunk), lj[10] (logit exchange). No big arrays, no LDS
// inner loop, nothing to spill.
//
// Lane map: lane = c + 10*b_sub (b_sub<6; lanes 60..63 idle = 93.75% util).
// Block 256 = 4 waves = 24 b. Grid (NCH=48 i-chunks, 22 b-groups).
// Softmax logits exchanged across the 10-lane c-group via __shfl.
// Per-chunk partials (no atomics) -> reduce+squash kernel.

#define NCH 48
#define IPC 24              // 1152 / NCH
#define CD 160

__device__ __forceinline__ float dot8(const float* __restrict__ w,
                                      const float4 ua, const float4 ub) {
    const float4* wp = (const float4*)w;
    const float4 w0 = wp[0];
    const float4 w1 = wp[1];
    return w0.x * ua.x + w0.y * ua.y + w0.z * ua.z + w0.w * ua.w
         + w1.x * ub.x + w1.y * ub.y + w1.z * ub.z + w1.w * ub.w;
}

template <int PASS>
__global__ __launch_bounds__(256, 4)
void pass_kernel(const float* __restrict__ u, const float* __restrict__ W,
                 const float* __restrict__ v0g, const float* __restrict__ v1g,
                 float* __restrict__ part, float* __restrict__ s_atomic)
{
    const int t    = threadIdx.x;
    const int lane = t & 63;
    const int wv   = t >> 6;
    const int bsub = lane / 10;           // 0..6 (6 => idle lane)
    const int c    = lane - bsub * 10;    // 0..9
    const bool lane_ok = (bsub < 6);
    const int b    = blockIdx.y * 24 + wv * 6 + bsub;
    const bool valid = lane_ok && (b < 512);
    const int bc   = valid ? b : 511;     // clamped for unguarded loads
    const int base = lane_ok ? bsub * 10 : 0;   // shfl group base
    const int i0   = blockIdx.x * IPC;

    // v[c][0..15] — i-invariant, lives in registers for the whole kernel.
    float v[16];
    #pragma unroll
    for (int d = 0; d < 16; ++d) v[d] = 0.0f;
    if (PASS >= 1) {
        const float* vp = v0g + ((size_t)bc * 10 + c) * 16;
        #pragma unroll
        for (int d = 0; d < 16; ++d) v[d] = vp[d];
        if (PASS >= 2) {
            const float* vq = v1g + ((size_t)bc * 10 + c) * 16;
            #pragma unroll
            for (int d = 0; d < 16; ++d) v[d] += vq[d];
        }
    }

    float s_acc[16];
    #pragma unroll
    for (int d = 0; d < 16; ++d) s_acc[d] = 0.0f;

    for (int ii = 0; ii < IPC; ++ii) {
        const int i = i0 + ii;

        const float4* up = (const float4*)(u + ((size_t)bc * 1152 + i) * 8);
        const float4 ua = up[0];
        const float4 ub = up[1];

        // W[i, c, d, 0:8] — this thread's 512 B c-slab.
        const float* Wp = W + ((size_t)i * 10 + c) * 128;

        float h[16];
        #pragma unroll
        for (int d = 0; d < 16; ++d) h[d] = dot8(Wp + d * 8, ua, ub);

        if (PASS == 0) {
            #pragma unroll
            for (int d = 0; d < 16; ++d) s_acc[d] += h[d];
        } else {
            float lg = 0.0f;
            #pragma unroll
            for (int d = 0; d < 16; ++d) lg += h[d] * v[d];

            float lj[10];
            #pragma unroll
            for (int j = 0; j < 10; ++j) lj[j] = __shfl(lg, base + j);

            float m = lj[0];
            #pragma unroll
            for (int j = 1; j < 10; ++j) m = fmaxf(m, lj[j]);
            float sum = 0.0f;
            #pragma unroll
            for (int j = 0; j < 10; ++j) sum += __expf(lj[j] - m);
            const float coef = __expf(lg - m) / sum;

            #pragma unroll
            for (int d = 0; d < 16; ++d) s_acc[d] += coef * h[d];
        }
    }

    if (PASS == 0) {
        #pragma unroll
        for (int d = 0; d < 16; ++d) s_acc[d] *= 0.1f;   // softmax(0) = 1/10
    }

    if (valid) {
        if (part) {
            float4* po = (float4*)(part + ((size_t)blockIdx.x * 512 + b) * CD + c * 16);
            po[0] = make_float4(s_acc[0],  s_acc[1],  s_acc[2],  s_acc[3]);
            po[1] = make_float4(s_acc[4],  s_acc[5],  s_acc[6],  s_acc[7]);
            po[2] = make_float4(s_acc[8],  s_acc[9],  s_acc[10], s_acc[11]);
            po[3] = make_float4(s_acc[12], s_acc[13], s_acc[14], s_acc[15]);
        } else {
#if defined(__HIP_DEVICE_COMPILE__)
            #pragma unroll
            for (int d = 0; d < 16; ++d)
                unsafeAtomicAdd(&s_atomic[((size_t)b * 10 + c) * 16 + d], s_acc[d]);
#endif
        }
    }
}

// Sum NCH partials and squash. 8 b-rows per block, grid 64.
__global__ void reduce_squash(const float* __restrict__ part, float* __restrict__ vout)
{
    __shared__ float acc_s[8 * CD];
    const int t  = threadIdx.x;
    const int b0 = blockIdx.x * 8;

    float acc[5] = {0.f, 0.f, 0.f, 0.f, 0.f};
    for (int ch = 0; ch < NCH; ++ch) {
        const float* p = part + ((size_t)ch * 512 + b0) * CD;
        #pragma unroll
        for (int j = 0; j < 5; ++j) acc[j] += p[t + 256 * j];
    }
    #pragma unroll
    for (int j = 0; j < 5; ++j) acc_s[t + 256 * j] = acc[j];
    __syncthreads();

    if (t < 80) {   // 8 b x 10 c rows
        float sv[16];
        float ns = 0.0f;
        #pragma unroll
        for (int d = 0; d < 16; ++d) {
            float x = acc_s[t * 16 + d];
            sv[d] = x;
            ns += x * x;
        }
        float scale = ns / ((1.0f + ns) * (sqrtf(ns) + 1e-8f));
        float* o = vout + ((size_t)b0 * 10 + t) * 16;
        #pragma unroll
        for (int d = 0; d < 16; ++d) o[d] = sv[d] * scale;
    }
}

// Fallback squash (atomic path): one thread per (b,c) row.
__global__ void squash_only(const float* __restrict__ s, float* __restrict__ vout)
{
    int r = blockIdx.x * 256 + threadIdx.x;
    if (r >= 512 * 10) return;
    const float* sp = s + (size_t)r * 16;
    float sv[16];
    float ns = 0.0f;
    #pragma unroll
    for (int d = 0; d < 16; ++d) {
        float x = sp[d];
        sv[d] = x;
        ns += x * x;
    }
    float scale = ns / ((1.0f + ns) * (sqrtf(ns) + 1e-8f));
    float* o = vout + (size_t)r * 16;
    #pragma unroll
    for (int d = 0; d < 16; ++d) o[d] = sv[d] * scale;
}

extern "C" void kernel_launch(void* const* d_in, const int* in_sizes, int n_in,
                              void* d_out, int out_size, void* d_ws, size_t ws_size,
                              hipStream_t stream)
{
    const float* u = (const float*)d_in[0];   // [512,1152,8]
    const float* W = (const float*)d_in[1];   // [1152,10,16,8]
    float* out = (float*)d_out;               // [512,10,16]

    float* v0 = (float*)d_ws;                 // 81920 f32
    float* v1 = v0 + 81920;                   // 81920 f32

    const size_t needA =
        ((size_t)2 * 81920 + (size_t)NCH * 512 * CD) * sizeof(float); // ~16.4 MB

    dim3 grid(NCH, 22);   // 22 * 24 >= 512 b
    dim3 blk(256);

    if (ws_size >= needA) {
        float* part = v1 + 81920;             // [48][512][160] f32
        pass_kernel<0><<<grid, blk, 0, stream>>>(u, W, nullptr, nullptr, part, nullptr);
        reduce_squash<<<64, 256, 0, stream>>>(part, v0);
        pass_kernel<1><<<grid, blk, 0, stream>>>(u, W, v0, nullptr, part, nullptr);
        reduce_squash<<<64, 256, 0, stream>>>(part, v1);
        pass_kernel<2><<<grid, blk, 0, stream>>>(u, W, v0, v1, part, nullptr);
        reduce_squash<<<64, 256, 0, stream>>>(part, out);
    } else {
        // Low-workspace fallback: single s buffer + global fp32 atomics.
        float* s = v1 + 81920;                // 81920 f32
        hipMemsetAsync(s, 0, 81920 * sizeof(float), stream);
        pass_kernel<0><<<grid, blk, 0, stream>>>(u, W, nullptr, nullptr, nullptr, s);
        squash_only<<<20, 256, 0, stream>>>(s, v0);
        hipMemsetAsync(s, 0, 81920 * sizeof(float), stream);
        pass_kernel<1><<<grid, blk, 0, stream>>>(u, W, v0, nullptr, nullptr, s);
        squash_only<<<20, 256, 0, stream>>>(s, v1);
        hipMemsetAsync(s, 0, 81920 * sizeof(float), stream);
        pass_kernel<2><<<grid, blk, 0, stream>>>(u, W, v0, v1, nullptr, s);
        squash_only<<<20, 256, 0, stream>>>(s, out);
    }
}